// Round 8
// baseline (576.244 us; speedup 1.0000x reference)
//
#include <hip/hip_runtime.h>
#include <hip/hip_bf16.h>

// Problem constants (B=4, T=4096, C=1024, NH=16, DH=128, DQKV=2048, DR=256)
#define TB 4
#define TT 4096
#define TC 1024
#define TNH 16
#define TDH 128
#define TDQKV 2048
#define TDR 256
#define RB 4096               // rows per batch chunk (= T)
#define ROWS (TB*TT)          // 16384
#define SLAB (RB*128)         // shorts per head-slab (one chunk)
#define NSEG 128              // segments per head per chunk (SEGT = 32)
#define SEGT 32

typedef __attribute__((ext_vector_type(8))) short bfx8;
typedef __attribute__((ext_vector_type(4))) float fx4;
typedef __attribute__((address_space(1))) const unsigned char GAS;
typedef __attribute__((address_space(3))) unsigned char LAS;

__device__ __forceinline__ unsigned short f2b(float f) {
    unsigned int u = __float_as_uint(f);
    unsigned int r = (u + 0x7fffu + ((u >> 16) & 1u)) >> 16;   // RNE
    return (unsigned short)r;
}
__device__ __forceinline__ float b2f(unsigned short h) {
    return __uint_as_float(((unsigned int)h) << 16);
}
__device__ __forceinline__ float sigm(float x) {
    return 1.0f / (1.0f + __expf(-x));
}
// bijective XCD swizzle (all our grids have nwg % 8 == 0)
__device__ __forceinline__ int xcd_swz(int hw, int nwg) {
    int q = nwg >> 3;
    return (hw & 7) * q + (hw >> 3);
}

// ---------------- fused setup: 4 weight cvts + rope table, one launch ----------------
__global__ __launch_bounds__(256) void setup_all(const float* __restrict__ wq1, unsigned short* __restrict__ w1b,
                                                 const float* __restrict__ wq2, unsigned short* __restrict__ w2b,
                                                 const float* __restrict__ wc1, unsigned short* __restrict__ wp1b,
                                                 const float* __restrict__ wc2, unsigned short* __restrict__ wp2b,
                                                 float* __restrict__ ct, float* __restrict__ st) {
    int blk = blockIdx.x;
    if (blk < 2816) {
        const float* in; unsigned short* out; int base;
        if (blk < 256)       { in = wq1; out = w1b;  base = blk; }
        else if (blk < 1792) { in = wq2; out = w2b;  base = blk - 256; }
        else if (blk < 2304) { in = wc1; out = wp1b; base = blk - 1792; }
        else                 { in = wc2; out = wp2b; base = blk - 2304; }
        int i = (base * 256 + threadIdx.x) * 4;
        float4 v = *(const float4*)(in + i);
        out[i + 0] = f2b(v.x);
        out[i + 1] = f2b(v.y);
        out[i + 2] = f2b(v.z);
        out[i + 3] = f2b(v.w);
    } else {
        int i = (blk - 2816) * 256 + threadIdx.x;   // < T*32
        int t = i >> 5, j = i & 31;
        float fr = exp2f(-10.0f * (float)j / 31.0f);   // (1/1024)^(j/31)
        float th = (float)t * fr;
        ct[i] = cosf(th);
        st[i] = sinf(th);
    }
}

// ---------------- RMSNorm(x) -> bf16, one block per row of 1024 ----------------
__global__ __launch_bounds__(256) void rmsnorm_x(const float* __restrict__ x,
                                                 unsigned short* __restrict__ xn) {
    int row = blockIdx.x;
    int tid = threadIdx.x;
    float4 v = *(const float4*)(x + (size_t)row * TC + tid * 4);
    float ss = v.x * v.x + v.y * v.y + v.z * v.z + v.w * v.w;
    #pragma unroll
    for (int o = 32; o > 0; o >>= 1) ss += __shfl_xor(ss, o);
    __shared__ float red[4];
    if ((tid & 63) == 0) red[tid >> 6] = ss;
    __syncthreads();
    float tot = red[0] + red[1] + red[2] + red[3];
    float sc = rsqrtf(tot * (1.0f / TC) + 1.1920929e-7f);
    unsigned short* o = xn + (size_t)row * TC + tid * 4;
    o[0] = f2b(v.x * sc); o[1] = f2b(v.y * sc); o[2] = f2b(v.z * sc); o[3] = f2b(v.w * sc);
}

// ---------------- 128(M)x64(N) skinny-N GEMM: wave-tile 64x32, 8 MFMA/step ----------------
template <int EPI, int NX>
__global__ __launch_bounds__(256) void gemm_sk(const unsigned short* __restrict__ A, int lda,
                                               const unsigned short* __restrict__ Bm,
                                               unsigned short* __restrict__ C, int ldc,
                                               int K) {
    __shared__ unsigned short As[2][128 * 32];
    __shared__ unsigned short Bs[2][64 * 32];
    const int lg = xcd_swz(blockIdx.x, gridDim.x);
    const int n0 = (lg % NX) * 64;
    const int m0 = (lg / NX) * 128;
    const int tid = threadIdx.x;
    const int lane = tid & 63;
    const int w = tid >> 6;
    const int wr = w >> 1, wc = w & 1;       // wave tile: 64 rows x 32 cols
    const int r16 = lane & 15;
    const int kk = (lane >> 4) * 8;
    const int l4 = lane >> 2;
    const int c8 = (lane & 3) * 8;
    const int nk = K >> 5;
    fx4 acc[4][2] = {};

    auto stage = [&](int buf, int k0) {
        #pragma unroll
        for (int i = 0; i < 2; ++i) {
            int rr = (w + 4 * i) * 16 + l4;
            const unsigned short* ga = A + (size_t)(m0 + rr) * lda + k0 + c8;
            __builtin_amdgcn_global_load_lds((GAS*)ga, (LAS*)&As[buf][(w + 4 * i) * 512], 16, 0, 0);
        }
        const unsigned short* gb = Bm + (size_t)(n0 + w * 16 + l4) * K + k0 + c8;
        __builtin_amdgcn_global_load_lds((GAS*)gb, (LAS*)&Bs[buf][w * 512], 16, 0, 0);
    };

    stage(0, 0);
    __syncthreads();
    int buf = 0;
    for (int ks = 0; ks < nk; ++ks) {
        if (ks + 1 < nk) stage(buf ^ 1, (ks + 1) * 32);
        bfx8 af[4], bfr[2];
        #pragma unroll
        for (int mi = 0; mi < 4; mi++) af[mi] = *(const bfx8*)&As[buf][(wr * 64 + mi * 16 + r16) * 32 + kk];
        #pragma unroll
        for (int ni = 0; ni < 2; ni++) bfr[ni] = *(const bfx8*)&Bs[buf][(wc * 32 + ni * 16 + r16) * 32 + kk];
        #pragma unroll
        for (int mi = 0; mi < 4; mi++)
            #pragma unroll
            for (int ni = 0; ni < 2; ni++)
                acc[mi][ni] = __builtin_amdgcn_mfma_f32_16x16x32_bf16(af[mi], bfr[ni], acc[mi][ni], 0, 0, 0);
        __syncthreads();
        buf ^= 1;
    }

    const int rg = lane >> 4;
    #pragma unroll
    for (int mi = 0; mi < 4; mi++)
        #pragma unroll
        for (int ni = 0; ni < 2; ni++) {
            int col = n0 + wc * 32 + ni * 16 + r16;
            #pragma unroll
            for (int r = 0; r < 4; r++) {
                int row = m0 + wr * 64 + mi * 16 + rg * 4 + r;
                float v = acc[mi][ni][r];
                if (EPI == 1) { v = fmaxf(v, 0.0f); v *= v; }
                C[(size_t)row * ldc + col] = f2b(v);
            }
        }
}

// ---------------- gemm2 fused with q/k rmsnorm+rope + p=sigm(k)*v + seg sums ----------------
// block = (head h, 64-row tile mb); computes full 384 cols {q,k,v} of head h.
// writes q_rope -> slab h, p -> slab 16+h; v never materialized; seg sums -> part.
__global__ __launch_bounds__(256) void gemm2f(const unsigned short* __restrict__ A,   // hbuf chunk [RB][256]
                                              const unsigned short* __restrict__ W,   // w2b [6144][256]
                                              unsigned short* __restrict__ qkv,
                                              const float* __restrict__ ct,
                                              const float* __restrict__ st,
                                              float* __restrict__ part) {
    __shared__ unsigned short As[2][64 * 32];
    __shared__ unsigned short Bs[2][384 * 32];
    __shared__ float psum[4][128];
    const int lg = xcd_swz(blockIdx.x, 1024);
    const int h = lg >> 6, mb = lg & 63;
    const int m0 = mb * 64;
    const int tid = threadIdx.x;
    const int lane = tid & 63;
    const int w = tid >> 6;
    const int r16 = lane & 15;
    const int rg = lane >> 4;
    const int kk = rg * 8;
    const int l4 = lane >> 2;
    const int c8 = (lane & 3) * 8;
    const int sec0 = h * 128, sec1 = 2048 + h * 128, sec2 = 4096 + h * 128;
    fx4 acc[24] = {};

    auto stage = [&](int buf, int k0) {
        __builtin_amdgcn_global_load_lds((GAS*)(A + (size_t)(m0 + w * 16 + l4) * TDR + k0 + c8),
                                         (LAS*)&As[buf][w * 512], 16, 0, 0);
        #pragma unroll
        for (int i = 0; i < 6; ++i) {
            int c = w + 4 * i;                     // B-tile chunk 0..23 (16 rows each)
            int sec = c >> 3;
            int grow = (sec == 0 ? sec0 : (sec == 1 ? sec1 : sec2)) + (c & 7) * 16 + l4;
            __builtin_amdgcn_global_load_lds((GAS*)(W + (size_t)grow * TDR + k0 + c8),
                                             (LAS*)&Bs[buf][c * 512], 16, 0, 0);
        }
    };

    stage(0, 0);
    __syncthreads();
    int buf = 0;
    for (int ks = 0; ks < 8; ++ks) {               // K = 256
        if (ks + 1 < 8) stage(buf ^ 1, (ks + 1) * 32);
        bfx8 af = *(const bfx8*)&As[buf][(w * 16 + r16) * 32 + kk];
        #pragma unroll
        for (int ni = 0; ni < 24; ++ni) {
            bfx8 bb = *(const bfx8*)&Bs[buf][(ni * 16 + r16) * 32 + kk];
            acc[ni] = __builtin_amdgcn_mfma_f32_16x16x32_bf16(af, bb, acc[ni], 0, 0, 0);
        }
        __syncthreads();
        buf ^= 1;
    }

    // epilogue: wave w owns rows m0+w*16 .. +15; lane holds cols ni*16+r16 (ni: 0-7 q, 8-15 k, 16-23 v)
    unsigned short* qs = qkv + (size_t)h * SLAB;
    unsigned short* ps = qkv + (size_t)(16 + h) * SLAB;
    float pseg[8] = {};
    #pragma unroll
    for (int r = 0; r < 4; ++r) {
        int t = m0 + w * 16 + rg * 4 + r;
        float ssq = 0.0f, ssk = 0.0f;
        #pragma unroll
        for (int ni = 0; ni < 8; ++ni) {
            ssq += acc[ni][r] * acc[ni][r];
            ssk += acc[8 + ni][r] * acc[8 + ni][r];
        }
        #pragma unroll
        for (int o = 1; o < 16; o <<= 1) { ssq += __shfl_xor(ssq, o); ssk += __shfl_xor(ssk, o); }
        float qsc = rsqrtf(ssq * (1.0f / TDH) + 1.1920929e-7f);
        float ksc = rsqrtf(ssk * (1.0f / TDH) + 1.1920929e-7f);
        #pragma unroll
        for (int j = 0; j < 4; ++j) {
            int d = j * 16 + r16;                  // < 64
            float c = 1.0f, s = 0.0f;
            if (j < 2) { c = ct[t * 32 + d]; s = st[t * 32 + d]; }   // d < 32: real rope
            float z1q = acc[j][r] * qsc,      z2q = acc[j + 4][r] * qsc;
            float z1k = acc[8 + j][r] * ksc,  z2k = acc[12 + j][r] * ksc;
            float qlo = z1q * c + z2q * s, qhi = z2q * c - z1q * s;
            float klo = z1k * c + z2k * s, khi = z2k * c - z1k * s;
            float plo = sigm(klo) * acc[16 + j][r];
            float phi = sigm(khi) * acc[20 + j][r];
            qs[(size_t)t * 128 + d]      = f2b(qlo);
            qs[(size_t)t * 128 + 64 + d] = f2b(qhi);
            ps[(size_t)t * 128 + d]      = f2b(plo);
            ps[(size_t)t * 128 + 64 + d] = f2b(phi);
            pseg[j] += plo;
            pseg[j + 4] += phi;
        }
    }
    #pragma unroll
    for (int j = 0; j < 8; ++j) {                  // reduce over rg (16 rows of the wave)
        pseg[j] += __shfl_xor(pseg[j], 16);
        pseg[j] += __shfl_xor(pseg[j], 32);
    }
    if (lane < 16) {
        #pragma unroll
        for (int j = 0; j < 8; ++j) psum[w][j * 16 + lane] = pseg[j];
    }
    __syncthreads();
    int sg = tid >> 7, d = tid & 127;              // 2 segments of 32 rows
    part[((size_t)h * NSEG + mb * 2 + sg) * 128 + d] = psum[sg * 2][d] + psum[sg * 2 + 1][d];
}

// ---------------- gemm4 fused with final, 128x(64u+64g) tiles: out = x + u*silu(g) -------
__global__ __launch_bounds__(256) void gemm4f128(const unsigned short* __restrict__ A,
                                                 const unsigned short* __restrict__ Wm,
                                                 const float* __restrict__ x,
                                                 float* __restrict__ out) {
    __shared__ unsigned short As[2][128 * 32];
    __shared__ unsigned short Bu[2][64 * 32];
    __shared__ unsigned short Bg[2][64 * 32];
    const int lg = xcd_swz(blockIdx.x, gridDim.x);   // 2048 blocks
    const int n0 = (lg & 15) * 64;            // u col block within 1024
    const int m0 = (lg >> 4) * 128;
    const int tid = threadIdx.x;
    const int lane = tid & 63;
    const int w = tid >> 6;
    const int wr = w >> 1, wc = w & 1;        // wave tile 64 rows x 32 cols (for each of u,g)
    const int r16 = lane & 15;
    const int rg = lane >> 4;
    const int kk = rg * 8;
    const int l4 = lane >> 2;
    const int c8 = (lane & 3) * 8;
    fx4 accu[4][2] = {};
    fx4 accg[4][2] = {};

    auto stage = [&](int buf, int k0) {
        #pragma unroll
        for (int i = 0; i < 2; ++i) {
            int rr = (w + 4 * i) * 16 + l4;
            __builtin_amdgcn_global_load_lds((GAS*)(A + (size_t)(m0 + rr) * TDR + k0 + c8),
                                             (LAS*)&As[buf][(w + 4 * i) * 512], 16, 0, 0);
        }
        int rr = w * 16 + l4;
        __builtin_amdgcn_global_load_lds((GAS*)(Wm + (size_t)(n0 + rr) * TDR + k0 + c8),
                                         (LAS*)&Bu[buf][w * 512], 16, 0, 0);
        __builtin_amdgcn_global_load_lds((GAS*)(Wm + (size_t)(1024 + n0 + rr) * TDR + k0 + c8),
                                         (LAS*)&Bg[buf][w * 512], 16, 0, 0);
    };

    stage(0, 0);
    __syncthreads();
    int buf = 0;
    for (int ks = 0; ks < 8; ++ks) {          // K = 256
        if (ks + 1 < 8) stage(buf ^ 1, (ks + 1) * 32);
        bfx8 af[4], bu[2], bg[2];
        #pragma unroll
        for (int mi = 0; mi < 4; mi++) af[mi] = *(const bfx8*)&As[buf][(wr * 64 + mi * 16 + r16) * 32 + kk];
        #pragma unroll
        for (int ni = 0; ni < 2; ni++) {
            bu[ni] = *(const bfx8*)&Bu[buf][(wc * 32 + ni * 16 + r16) * 32 + kk];
            bg[ni] = *(const bfx8*)&Bg[buf][(wc * 32 + ni * 16 + r16) * 32 + kk];
        }
        #pragma unroll
        for (int mi = 0; mi < 4; mi++)
            #pragma unroll
            for (int ni = 0; ni < 2; ni++) {
                accu[mi][ni] = __builtin_amdgcn_mfma_f32_16x16x32_bf16(af[mi], bu[ni], accu[mi][ni], 0, 0, 0);
                accg[mi][ni] = __builtin_amdgcn_mfma_f32_16x16x32_bf16(af[mi], bg[ni], accg[mi][ni], 0, 0, 0);
            }
        __syncthreads();
        buf ^= 1;
    }

    #pragma unroll
    for (int mi = 0; mi < 4; mi++)
        #pragma unroll
        for (int ni = 0; ni < 2; ni++) {
            int col = n0 + wc * 32 + ni * 16 + r16;      // < 1024
            #pragma unroll
            for (int r = 0; r < 4; r++) {
                int row = m0 + wr * 64 + mi * 16 + rg * 4 + r;
                float u = accu[mi][ni][r];
                float g = accg[mi][ni][r];
                size_t idx = (size_t)row * TC + col;
                out[idx] = x[idx] + u * (g * sigm(g));
            }
        }
}

// ---------------- phase B: exclusive prefix over NSEG segments per (h,d) ----------------
__global__ __launch_bounds__(256) void scanB128(float* __restrict__ part) {
    int idx = blockIdx.x * 256 + threadIdx.x;   // < 2048 chains
    int h = idx >> 7, d = idx & 127;
    float run = 0.0f;
    #pragma unroll 8
    for (int s = 0; s < NSEG; ++s) {
        float* p = part + ((size_t)(h * NSEG + s)) * 128 + d;
        float tv = *p;
        *p = run;
        run += tv;
    }
}

// ---------------- phase C: y = relu(q) * cumsum(p) -> y row-major (d_out slice) ----------
__global__ __launch_bounds__(256) void scanC3(const unsigned short* __restrict__ qkv,
                                              const float* __restrict__ part,
                                              unsigned short* __restrict__ y) {
    const int bseg = blockIdx.x & 7, h = blockIdx.x >> 3;
    const int g = threadIdx.x >> 4, l16 = threadIdx.x & 15;
    const int seg = bseg * 16 + g;
    const int d0 = l16 * 8;
    const unsigned short* qp = qkv + (size_t)h * SLAB;
    const unsigned short* pp = qkv + (size_t)(16 + h) * SLAB;
    float sum[8];
    const float* pb = part + ((size_t)(h * NSEG + seg)) * 128 + d0;
    *(float4*)&sum[0] = *(const float4*)pb;
    *(float4*)&sum[4] = *(const float4*)(pb + 4);
    #pragma unroll 4
    for (int i = 0; i < SEGT; ++i) {
        int t = seg * SEGT + i;
        size_t off = (size_t)t * 128 + d0;
        bfx8 pv = *(const bfx8*)(pp + off);
        bfx8 qv = *(const bfx8*)(qp + off);
        bfx8 ov;
        #pragma unroll
        for (int j = 0; j < 8; ++j) {
            sum[j] += b2f((unsigned short)pv[j]);
            float q = b2f((unsigned short)qv[j]);
            ov[j] = (short)f2b(fmaxf(q, 0.0f) * sum[j]);
        }
        *(bfx8*)(y + (size_t)t * 2048 + h * 128 + d0) = ov;
    }
}

extern "C" void kernel_launch(void* const* d_in, const int* in_sizes, int n_in,
                              void* d_out, int out_size, void* d_ws, size_t ws_size,
                              hipStream_t stream) {
    (void)in_sizes; (void)n_in; (void)out_size; (void)ws_size;
    const float* x    = (const float*)d_in[0];
    const float* wq1  = (const float*)d_in[1];   // [256,1024]
    const float* wq2  = (const float*)d_in[2];   // [6144,256]
    const float* wc1  = (const float*)d_in[3];   // [256,2048]
    const float* wc2  = (const float*)d_in[4];   // [2048,256]
    float* out = (float*)d_out;

    char* ws = (char*)d_ws;
    size_t off = 0;
    auto alloc = [&](size_t bytes) -> void* {
        off = (off + 255) & ~(size_t)255;
        void* p = ws + off;
        off += bytes;
        return p;
    };
    // pool: max(qkvb 33.5 (32 slabs), xn 33.5, t1 8.4) MB -- live ranges disjoint
    char* pool = (char*)alloc((size_t)RB * 4096 * 2);          // 33.5 MB
    unsigned short* qkvb = (unsigned short*)pool;              // head-major: 32 slabs [RB][128] (q, p)
    unsigned short* xn   = (unsigned short*)pool;              // alias (ROWS x 1024)
    unsigned short* t1   = (unsigned short*)pool;              // alias (ROWS x 256)
    unsigned short* hbuf = (unsigned short*)alloc((size_t)ROWS * TDR * 2);      // 8.4 MB
    unsigned short* w1b  = (unsigned short*)alloc((size_t)TDR * TC * 2);
    unsigned short* w2b  = (unsigned short*)alloc((size_t)3 * TDQKV * TDR * 2);
    unsigned short* wp1b = (unsigned short*)alloc((size_t)TDR * TDQKV * 2);
    unsigned short* wp2b = (unsigned short*)alloc((size_t)2 * TC * TDR * 2);
    float* ct   = (float*)alloc((size_t)TT * 32 * 4);
    float* st   = (float*)alloc((size_t)TT * 32 * 4);
    float* part = (float*)alloc((size_t)TNH * NSEG * 128 * 4);  // 1 MB
    unsigned short* ybuf = (unsigned short*)d_out;             // y lives in d_out (bf16 16384x2048)

    // fused setup (one launch)
    setup_all<<<3328, 256, 0, stream>>>(wq1, w1b, wq2, w2b, wc1, wp1b, wc2, wp2b, ct, st);

    // all-rows: rmsnorm + gemm1 (xn -> h) with relu^2
    rmsnorm_x<<<ROWS, 256, 0, stream>>>(x, xn);
    gemm_sk<1, 4><<<(ROWS / 128) * (TDR / 64), 256, 0, stream>>>(
        xn, TC, w1b, hbuf, TDR, TC);

    // per-batch-chunk: fused gemm2+post -> scanB128 -> scanC3
    for (int b = 0; b < TB; ++b) {
        gemm2f<<<1024, 256, 0, stream>>>(
            hbuf + (size_t)b * RB * TDR, w2b, qkvb, ct, st, part);
        scanB128<<<(TNH * 128) / 256, 256, 0, stream>>>(part);
        scanC3<<<TNH * 8, 256, 0, stream>>>(qkvb, part, ybuf + (size_t)b * RB * 2048);
    }

    // all-rows tail: gemm3 (y -> t1), fused gemm4+final -> f32 out
    gemm_sk<0, 4><<<(ROWS / 128) * (TDR / 64), 256, 0, stream>>>(
        ybuf, 2048, wp1b, t1, TDR, TDQKV);
    gemm4f128<<<(ROWS / 128) * (TC / 64), 256, 0, stream>>>(t1, wp2b, x, out);
}

// Round 9
// 427.836 us; speedup vs baseline: 1.3469x; 1.3469x over previous
//
#include <hip/hip_runtime.h>
#include <hip/hip_bf16.h>

// Problem constants (B=4, T=4096, C=1024, NH=16, DH=128, DQKV=2048, DR=256)
#define TB 4
#define TT 4096
#define TC 1024
#define TNH 16
#define TDH 128
#define TDQKV 2048
#define TDR 256
#define RB 4096               // rows per batch chunk (= T)
#define ROWS (TB*TT)          // 16384
#define SLAB (RB*128)         // shorts per head-slab (one chunk)
#define NSEG 128              // segments per head per chunk (SEGT = 32)
#define SEGT 32

typedef __attribute__((ext_vector_type(8))) short bfx8;
typedef __attribute__((ext_vector_type(4))) float fx4;
typedef __attribute__((address_space(1))) const unsigned char GAS;
typedef __attribute__((address_space(3))) unsigned char LAS;

__device__ __forceinline__ unsigned short f2b(float f) {
    unsigned int u = __float_as_uint(f);
    unsigned int r = (u + 0x7fffu + ((u >> 16) & 1u)) >> 16;   // RNE
    return (unsigned short)r;
}
__device__ __forceinline__ float b2f(unsigned short h) {
    return __uint_as_float(((unsigned int)h) << 16);
}
__device__ __forceinline__ float sigm(float x) {
    return 1.0f / (1.0f + __expf(-x));
}
// bijective XCD swizzle (all our grids have nwg % 8 == 0)
__device__ __forceinline__ int xcd_swz(int hw, int nwg) {
    int q = nwg >> 3;
    return (hw & 7) * q + (hw >> 3);
}

// ---------------- fused setup: 4 weight cvts + rope table, one launch ----------------
__global__ __launch_bounds__(256) void setup_all(const float* __restrict__ wq1, unsigned short* __restrict__ w1b,
                                                 const float* __restrict__ wq2, unsigned short* __restrict__ w2b,
                                                 const float* __restrict__ wc1, unsigned short* __restrict__ wp1b,
                                                 const float* __restrict__ wc2, unsigned short* __restrict__ wp2b,
                                                 float* __restrict__ ct, float* __restrict__ st) {
    int blk = blockIdx.x;
    if (blk < 2816) {
        const float* in; unsigned short* out; int base;
        if (blk < 256)       { in = wq1; out = w1b;  base = blk; }
        else if (blk < 1792) { in = wq2; out = w2b;  base = blk - 256; }
        else if (blk < 2304) { in = wc1; out = wp1b; base = blk - 1792; }
        else                 { in = wc2; out = wp2b; base = blk - 2304; }
        int i = (base * 256 + threadIdx.x) * 4;
        float4 v = *(const float4*)(in + i);
        out[i + 0] = f2b(v.x);
        out[i + 1] = f2b(v.y);
        out[i + 2] = f2b(v.z);
        out[i + 3] = f2b(v.w);
    } else {
        int i = (blk - 2816) * 256 + threadIdx.x;   // < T*32
        int t = i >> 5, j = i & 31;
        float fr = exp2f(-10.0f * (float)j / 31.0f);   // (1/1024)^(j/31)
        float th = (float)t * fr;
        ct[i] = cosf(th);
        st[i] = sinf(th);
    }
}

// ---------------- RMSNorm(x) -> bf16, one block per row of 1024 ----------------
__global__ __launch_bounds__(256) void rmsnorm_x(const float* __restrict__ x,
                                                 unsigned short* __restrict__ xn) {
    int row = blockIdx.x;
    int tid = threadIdx.x;
    float4 v = *(const float4*)(x + (size_t)row * TC + tid * 4);
    float ss = v.x * v.x + v.y * v.y + v.z * v.z + v.w * v.w;
    #pragma unroll
    for (int o = 32; o > 0; o >>= 1) ss += __shfl_xor(ss, o);
    __shared__ float red[4];
    if ((tid & 63) == 0) red[tid >> 6] = ss;
    __syncthreads();
    float tot = red[0] + red[1] + red[2] + red[3];
    float sc = rsqrtf(tot * (1.0f / TC) + 1.1920929e-7f);
    unsigned short* o = xn + (size_t)row * TC + tid * 4;
    o[0] = f2b(v.x * sc); o[1] = f2b(v.y * sc); o[2] = f2b(v.z * sc); o[3] = f2b(v.w * sc);
}

// ---------------- 128x128 bf16 GEMM (m97 2-phase), EPI=2: scatter to head-major qkv ----
// C layout (EPI=2): slab head_idx = col>>7 (48 slabs), addr = head*SLAB + row*128 + (col&127)
template <int EPI>
__global__ __launch_bounds__(256) void gemm_bt(const unsigned short* __restrict__ A, int lda,
                                               const unsigned short* __restrict__ Bm,
                                               unsigned short* __restrict__ C, int ldc,
                                               int N, int K) {
    __shared__ unsigned short As[2][128 * 32];
    __shared__ unsigned short Bs[2][128 * 32];
    const int m0 = blockIdx.y * 128;
    const int n0 = blockIdx.x * 128;
    const int tid = threadIdx.x;
    const int lane = tid & 63;
    const int w = tid >> 6;
    const int wr = w >> 1, wc = w & 1;
    const int r16 = lane & 15;
    const int kk = (lane >> 4) * 8;
    const int l4 = lane >> 2;
    const int c8 = (lane & 3) * 8;
    const int nk = K >> 5;
    fx4 acc[4][4] = {};

    auto stage = [&](int buf, int k0) {
        #pragma unroll
        for (int i = 0; i < 2; ++i) {
            int rr = (w + 4 * i) * 16 + l4;
            const unsigned short* ga = A + (size_t)(m0 + rr) * lda + k0 + c8;
            const unsigned short* gb = Bm + (size_t)(n0 + rr) * K + k0 + c8;
            __builtin_amdgcn_global_load_lds((GAS*)ga, (LAS*)&As[buf][(w + 4 * i) * 512], 16, 0, 0);
            __builtin_amdgcn_global_load_lds((GAS*)gb, (LAS*)&Bs[buf][(w + 4 * i) * 512], 16, 0, 0);
        }
    };

    stage(0, 0);
    __syncthreads();
    int buf = 0;
    for (int ks = 0; ks < nk; ++ks) {
        if (ks + 1 < nk) stage(buf ^ 1, (ks + 1) * 32);
        bfx8 af[4], bfr[4];
        #pragma unroll
        for (int mi = 0; mi < 4; mi++) af[mi] = *(const bfx8*)&As[buf][(wr * 64 + mi * 16 + r16) * 32 + kk];
        #pragma unroll
        for (int ni = 0; ni < 4; ni++) bfr[ni] = *(const bfx8*)&Bs[buf][(wc * 64 + ni * 16 + r16) * 32 + kk];
        #pragma unroll
        for (int mi = 0; mi < 4; mi++)
            #pragma unroll
            for (int ni = 0; ni < 4; ni++)
                acc[mi][ni] = __builtin_amdgcn_mfma_f32_16x16x32_bf16(af[mi], bfr[ni], acc[mi][ni], 0, 0, 0);
        __syncthreads();
        buf ^= 1;
    }

    const int rg = lane >> 4;
    #pragma unroll
    for (int mi = 0; mi < 4; mi++)
        #pragma unroll
        for (int ni = 0; ni < 4; ni++) {
            int col = n0 + wc * 64 + ni * 16 + r16;
            #pragma unroll
            for (int r = 0; r < 4; r++) {
                int row = m0 + wr * 64 + mi * 16 + rg * 4 + r;
                float v = acc[mi][ni][r];
                if (EPI == 1) { v = fmaxf(v, 0.0f); v *= v; }
                if (EPI == 2) {
                    int head = col >> 7;
                    C[(size_t)head * SLAB + (size_t)row * 128 + (col & 127)] = f2b(v);
                } else {
                    C[(size_t)row * ldc + col] = f2b(v);
                }
            }
        }
}

// ---------------- 128(M)x64(N) skinny-N GEMM: wave-tile 64x32, 8 MFMA/step ----------------
template <int EPI, int NX>
__global__ __launch_bounds__(256) void gemm_sk(const unsigned short* __restrict__ A, int lda,
                                               const unsigned short* __restrict__ Bm,
                                               unsigned short* __restrict__ C, int ldc,
                                               int K) {
    __shared__ unsigned short As[2][128 * 32];
    __shared__ unsigned short Bs[2][64 * 32];
    const int lg = xcd_swz(blockIdx.x, gridDim.x);
    const int n0 = (lg % NX) * 64;
    const int m0 = (lg / NX) * 128;
    const int tid = threadIdx.x;
    const int lane = tid & 63;
    const int w = tid >> 6;
    const int wr = w >> 1, wc = w & 1;       // wave tile: 64 rows x 32 cols
    const int r16 = lane & 15;
    const int kk = (lane >> 4) * 8;
    const int l4 = lane >> 2;
    const int c8 = (lane & 3) * 8;
    const int nk = K >> 5;
    fx4 acc[4][2] = {};

    auto stage = [&](int buf, int k0) {
        #pragma unroll
        for (int i = 0; i < 2; ++i) {
            int rr = (w + 4 * i) * 16 + l4;
            const unsigned short* ga = A + (size_t)(m0 + rr) * lda + k0 + c8;
            __builtin_amdgcn_global_load_lds((GAS*)ga, (LAS*)&As[buf][(w + 4 * i) * 512], 16, 0, 0);
        }
        const unsigned short* gb = Bm + (size_t)(n0 + w * 16 + l4) * K + k0 + c8;
        __builtin_amdgcn_global_load_lds((GAS*)gb, (LAS*)&Bs[buf][w * 512], 16, 0, 0);
    };

    stage(0, 0);
    __syncthreads();
    int buf = 0;
    for (int ks = 0; ks < nk; ++ks) {
        if (ks + 1 < nk) stage(buf ^ 1, (ks + 1) * 32);
        bfx8 af[4], bfr[2];
        #pragma unroll
        for (int mi = 0; mi < 4; mi++) af[mi] = *(const bfx8*)&As[buf][(wr * 64 + mi * 16 + r16) * 32 + kk];
        #pragma unroll
        for (int ni = 0; ni < 2; ni++) bfr[ni] = *(const bfx8*)&Bs[buf][(wc * 32 + ni * 16 + r16) * 32 + kk];
        #pragma unroll
        for (int mi = 0; mi < 4; mi++)
            #pragma unroll
            for (int ni = 0; ni < 2; ni++)
                acc[mi][ni] = __builtin_amdgcn_mfma_f32_16x16x32_bf16(af[mi], bfr[ni], acc[mi][ni], 0, 0, 0);
        __syncthreads();
        buf ^= 1;
    }

    const int rg = lane >> 4;
    #pragma unroll
    for (int mi = 0; mi < 4; mi++)
        #pragma unroll
        for (int ni = 0; ni < 2; ni++) {
            int col = n0 + wc * 32 + ni * 16 + r16;
            #pragma unroll
            for (int r = 0; r < 4; r++) {
                int row = m0 + wr * 64 + mi * 16 + rg * 4 + r;
                float v = acc[mi][ni][r];
                if (EPI == 1) { v = fmaxf(v, 0.0f); v *= v; }
                C[(size_t)row * ldc + col] = f2b(v);
            }
        }
}

// ---------------- gemm4 fused with final, 128x(64u+64g) tiles: out = x + u*silu(g) -------
__global__ __launch_bounds__(256) void gemm4f128(const unsigned short* __restrict__ A,
                                                 const unsigned short* __restrict__ Wm,
                                                 const float* __restrict__ x,
                                                 float* __restrict__ out) {
    __shared__ unsigned short As[2][128 * 32];
    __shared__ unsigned short Bu[2][64 * 32];
    __shared__ unsigned short Bg[2][64 * 32];
    const int lg = xcd_swz(blockIdx.x, gridDim.x);   // 2048 blocks
    const int n0 = (lg & 15) * 64;            // u col block within 1024
    const int m0 = (lg >> 4) * 128;
    const int tid = threadIdx.x;
    const int lane = tid & 63;
    const int w = tid >> 6;
    const int wr = w >> 1, wc = w & 1;        // wave tile 64 rows x 32 cols (for each of u,g)
    const int r16 = lane & 15;
    const int rg = lane >> 4;
    const int kk = rg * 8;
    const int l4 = lane >> 2;
    const int c8 = (lane & 3) * 8;
    fx4 accu[4][2] = {};
    fx4 accg[4][2] = {};

    auto stage = [&](int buf, int k0) {
        #pragma unroll
        for (int i = 0; i < 2; ++i) {
            int rr = (w + 4 * i) * 16 + l4;
            __builtin_amdgcn_global_load_lds((GAS*)(A + (size_t)(m0 + rr) * TDR + k0 + c8),
                                             (LAS*)&As[buf][(w + 4 * i) * 512], 16, 0, 0);
        }
        int rr = w * 16 + l4;
        __builtin_amdgcn_global_load_lds((GAS*)(Wm + (size_t)(n0 + rr) * TDR + k0 + c8),
                                         (LAS*)&Bu[buf][w * 512], 16, 0, 0);
        __builtin_amdgcn_global_load_lds((GAS*)(Wm + (size_t)(1024 + n0 + rr) * TDR + k0 + c8),
                                         (LAS*)&Bg[buf][w * 512], 16, 0, 0);
    };

    stage(0, 0);
    __syncthreads();
    int buf = 0;
    for (int ks = 0; ks < 8; ++ks) {          // K = 256
        if (ks + 1 < 8) stage(buf ^ 1, (ks + 1) * 32);
        bfx8 af[4], bu[2], bg[2];
        #pragma unroll
        for (int mi = 0; mi < 4; mi++) af[mi] = *(const bfx8*)&As[buf][(wr * 64 + mi * 16 + r16) * 32 + kk];
        #pragma unroll
        for (int ni = 0; ni < 2; ni++) {
            bu[ni] = *(const bfx8*)&Bu[buf][(wc * 32 + ni * 16 + r16) * 32 + kk];
            bg[ni] = *(const bfx8*)&Bg[buf][(wc * 32 + ni * 16 + r16) * 32 + kk];
        }
        #pragma unroll
        for (int mi = 0; mi < 4; mi++)
            #pragma unroll
            for (int ni = 0; ni < 2; ni++) {
                accu[mi][ni] = __builtin_amdgcn_mfma_f32_16x16x32_bf16(af[mi], bu[ni], accu[mi][ni], 0, 0, 0);
                accg[mi][ni] = __builtin_amdgcn_mfma_f32_16x16x32_bf16(af[mi], bg[ni], accg[mi][ni], 0, 0, 0);
            }
        __syncthreads();
        buf ^= 1;
    }

    #pragma unroll
    for (int mi = 0; mi < 4; mi++)
        #pragma unroll
        for (int ni = 0; ni < 2; ni++) {
            int col = n0 + wc * 32 + ni * 16 + r16;      // < 1024
            #pragma unroll
            for (int r = 0; r < 4; r++) {
                int row = m0 + wr * 64 + mi * 16 + rg * 4 + r;
                float u = accu[mi][ni][r];
                float g = accg[mi][ni][r];
                size_t idx = (size_t)row * TC + col;
                out[idx] = x[idx] + u * (g * sigm(g));
            }
        }
}

// ---------------- postKV: k RMSNorm+RoPE, p=sigm(k)*v over k-slab, 32-t seg sums ---------
// q is NOT touched (deferred to scanCQ). block = (h, 64-row tile); 256 thr;
// 16 lanes/row, lane owns 8 dims d0=l16*8; RoPE pair via shfl_xor(.,8).
__global__ __launch_bounds__(256) void postKV(unsigned short* __restrict__ qkv,
                                              const float* __restrict__ ct,
                                              const float* __restrict__ st,
                                              float* __restrict__ part) {
    const int tile = blockIdx.x & 63, h = blockIdx.x >> 6;
    const int g = threadIdx.x >> 4, l16 = threadIdx.x & 15;
    const int d0 = l16 * 8;
    const int dl = (l16 & 7) * 8;              // rope-freq dim base (within 64)
    const bool rot = dl < 32;
    const float se = (l16 < 8) ? 1.0f : -1.0f;
    unsigned short* ks = qkv + (size_t)(16 + h) * SLAB;
    const unsigned short* vs = qkv + (size_t)(32 + h) * SLAB;
    __shared__ float psum[2][16][128];
    float acc[2][8] = {};

    #pragma unroll
    for (int p4 = 0; p4 < 4; ++p4) {
        const int t = tile * 64 + p4 * 16 + g;
        const size_t off = (size_t)t * 128 + d0;
        bfx8 k8 = *(const bfx8*)(ks + off);
        float ka[8];
        #pragma unroll
        for (int j = 0; j < 8; ++j) ka[j] = b2f((unsigned short)k8[j]);
        float ssk = 0.0f;
        #pragma unroll
        for (int j = 0; j < 8; ++j) ssk += ka[j] * ka[j];
        #pragma unroll
        for (int o = 1; o < 16; o <<= 1) ssk += __shfl_xor(ssk, o);
        float ksc = rsqrtf(ssk * (1.0f / TDH) + 1.1920929e-7f);
        #pragma unroll
        for (int j = 0; j < 8; ++j) ka[j] *= ksc;
        float kb[8];
        #pragma unroll
        for (int j = 0; j < 8; ++j) kb[j] = __shfl_xor(ka[j], 8);
        float c[8], s[8];
        if (rot) {
            float4 c0 = *(const float4*)(ct + t * 32 + dl);
            float4 c1 = *(const float4*)(ct + t * 32 + dl + 4);
            float4 s0 = *(const float4*)(st + t * 32 + dl);
            float4 s1 = *(const float4*)(st + t * 32 + dl + 4);
            c[0]=c0.x; c[1]=c0.y; c[2]=c0.z; c[3]=c0.w; c[4]=c1.x; c[5]=c1.y; c[6]=c1.z; c[7]=c1.w;
            s[0]=s0.x; s[1]=s0.y; s[2]=s0.z; s[3]=s0.w; s[4]=s1.x; s[5]=s1.y; s[6]=s1.z; s[7]=s1.w;
        } else {
            #pragma unroll
            for (int j = 0; j < 8; ++j) { c[j] = 1.0f; s[j] = 0.0f; }
        }
        bfx8 v8 = *(const bfx8*)(vs + off);
        bfx8 po;
        const int h2 = p4 >> 1;
        #pragma unroll
        for (int j = 0; j < 8; ++j) {
            float kr = ka[j] * c[j] + kb[j] * (s[j] * se);
            float p = sigm(kr) * b2f((unsigned short)v8[j]);
            po[j] = (short)f2b(p);
            acc[h2][j] += p;
        }
        *(bfx8*)(ks + off) = po;               // p overwrites k (k dead afterwards)
    }
    #pragma unroll
    for (int h2 = 0; h2 < 2; ++h2)
        #pragma unroll
        for (int j = 0; j < 8; ++j) psum[h2][g][d0 + j] = acc[h2][j];
    __syncthreads();
    const int h2 = threadIdx.x >> 7, d = threadIdx.x & 127;
    float tot = 0.0f;
    #pragma unroll
    for (int gg = 0; gg < 16; ++gg) tot += psum[h2][gg][d];
    part[((size_t)h * NSEG + tile * 2 + h2) * 128 + d] = tot;
}

// ---------------- phase B: exclusive prefix over NSEG segments per (h,d) ----------------
__global__ __launch_bounds__(256) void scanB128(float* __restrict__ part) {
    int idx = blockIdx.x * 256 + threadIdx.x;   // < 2048 chains
    int h = idx >> 7, d = idx & 127;
    float run = 0.0f;
    #pragma unroll 8
    for (int s = 0; s < NSEG; ++s) {
        float* p = part + ((size_t)(h * NSEG + s)) * 128 + d;
        float tv = *p;
        *p = run;
        run += tv;
    }
}

// ---------------- scanCQ: q RMSNorm+RoPE+relu on the fly, y = relu(q_rope)*cumsum(p) -----
// block = (h, 4 segments); 64 thr = 4 seg-groups x 16 lanes; lane owns 8 dims.
__global__ __launch_bounds__(64) void scanCQ(const unsigned short* __restrict__ qkv,
                                             const float* __restrict__ part,
                                             unsigned short* __restrict__ y,
                                             const float* __restrict__ ct,
                                             const float* __restrict__ st) {
    const int bseg = blockIdx.x & 31, h = blockIdx.x >> 5;
    const int g = threadIdx.x >> 4, l16 = threadIdx.x & 15;
    const int seg = bseg * 4 + g;
    const int d0 = l16 * 8;
    const int dl = (l16 & 7) * 8;
    const bool rot = dl < 32;
    const float se = (l16 < 8) ? 1.0f : -1.0f;
    const unsigned short* qp = qkv + (size_t)h * SLAB;
    const unsigned short* pp = qkv + (size_t)(16 + h) * SLAB;
    float sum[8];
    const float* pb = part + ((size_t)(h * NSEG + seg)) * 128 + d0;
    *(float4*)&sum[0] = *(const float4*)pb;
    *(float4*)&sum[4] = *(const float4*)(pb + 4);
    for (int i = 0; i < SEGT; ++i) {
        const int t = seg * SEGT + i;
        const size_t off = (size_t)t * 128 + d0;
        bfx8 p8 = *(const bfx8*)(pp + off);
        bfx8 q8 = *(const bfx8*)(qp + off);
        float qa[8];
        #pragma unroll
        for (int j = 0; j < 8; ++j) qa[j] = b2f((unsigned short)q8[j]);
        float ssq = 0.0f;
        #pragma unroll
        for (int j = 0; j < 8; ++j) ssq += qa[j] * qa[j];
        #pragma unroll
        for (int o = 1; o < 16; o <<= 1) ssq += __shfl_xor(ssq, o);
        float qsc = rsqrtf(ssq * (1.0f / TDH) + 1.1920929e-7f);
        #pragma unroll
        for (int j = 0; j < 8; ++j) qa[j] *= qsc;
        float qb[8];
        #pragma unroll
        for (int j = 0; j < 8; ++j) qb[j] = __shfl_xor(qa[j], 8);
        float c[8], s[8];
        if (rot) {
            float4 c0 = *(const float4*)(ct + t * 32 + dl);
            float4 c1 = *(const float4*)(ct + t * 32 + dl + 4);
            float4 s0 = *(const float4*)(st + t * 32 + dl);
            float4 s1 = *(const float4*)(st + t * 32 + dl + 4);
            c[0]=c0.x; c[1]=c0.y; c[2]=c0.z; c[3]=c0.w; c[4]=c1.x; c[5]=c1.y; c[6]=c1.z; c[7]=c1.w;
            s[0]=s0.x; s[1]=s0.y; s[2]=s0.z; s[3]=s0.w; s[4]=s1.x; s[5]=s1.y; s[6]=s1.z; s[7]=s1.w;
        } else {
            #pragma unroll
            for (int j = 0; j < 8; ++j) { c[j] = 1.0f; s[j] = 0.0f; }
        }
        bfx8 ov;
        #pragma unroll
        for (int j = 0; j < 8; ++j) {
            float qr = qa[j] * c[j] + qb[j] * (s[j] * se);
            sum[j] += b2f((unsigned short)p8[j]);
            ov[j] = (short)f2b(fmaxf(qr, 0.0f) * sum[j]);
        }
        *(bfx8*)(y + (size_t)t * 2048 + h * 128 + d0) = ov;
    }
}

extern "C" void kernel_launch(void* const* d_in, const int* in_sizes, int n_in,
                              void* d_out, int out_size, void* d_ws, size_t ws_size,
                              hipStream_t stream) {
    (void)in_sizes; (void)n_in; (void)out_size; (void)ws_size;
    const float* x    = (const float*)d_in[0];
    const float* wq1  = (const float*)d_in[1];   // [256,1024]
    const float* wq2  = (const float*)d_in[2];   // [6144,256]
    const float* wc1  = (const float*)d_in[3];   // [256,2048]
    const float* wc2  = (const float*)d_in[4];   // [2048,256]
    float* out = (float*)d_out;

    char* ws = (char*)d_ws;
    size_t off = 0;
    auto alloc = [&](size_t bytes) -> void* {
        off = (off + 255) & ~(size_t)255;
        void* p = ws + off;
        off += bytes;
        return p;
    };
    // pool: max(qkvb 50.3 (48 slabs), xn 33.5, t1 8.4) MB -- live ranges disjoint
    char* pool = (char*)alloc((size_t)RB * 6144 * 2);          // 50.3 MB
    unsigned short* qkvb = (unsigned short*)pool;              // head-major: 48 slabs [RB][128]
    unsigned short* xn   = (unsigned short*)pool;              // alias (ROWS x 1024)
    unsigned short* t1   = (unsigned short*)pool;              // alias (ROWS x 256)
    unsigned short* hbuf = (unsigned short*)alloc((size_t)ROWS * TDR * 2);      // 8.4 MB
    unsigned short* w1b  = (unsigned short*)alloc((size_t)TDR * TC * 2);
    unsigned short* w2b  = (unsigned short*)alloc((size_t)3 * TDQKV * TDR * 2);
    unsigned short* wp1b = (unsigned short*)alloc((size_t)TDR * TDQKV * 2);
    unsigned short* wp2b = (unsigned short*)alloc((size_t)2 * TC * TDR * 2);
    float* ct   = (float*)alloc((size_t)TT * 32 * 4);
    float* st   = (float*)alloc((size_t)TT * 32 * 4);
    float* part = (float*)alloc((size_t)TNH * NSEG * 128 * 4);  // 1 MB
    unsigned short* ybuf = (unsigned short*)d_out;             // y lives in d_out (bf16 16384x2048)

    // fused setup (one launch)
    setup_all<<<3328, 256, 0, stream>>>(wq1, w1b, wq2, w2b, wc1, wp1b, wc2, wp2b, ct, st);

    // all-rows: rmsnorm + gemm1 (xn -> h) with relu^2
    rmsnorm_x<<<ROWS, 256, 0, stream>>>(x, xn);
    gemm_sk<1, 4><<<(ROWS / 128) * (TDR / 64), 256, 0, stream>>>(
        xn, TC, w1b, hbuf, TDR, TC);

    // per-batch-chunk: gemm2 (scatter head-major) -> postKV -> scanB128 -> scanCQ
    for (int b = 0; b < TB; ++b) {
        gemm_bt<2><<<dim3(6144 / 128, RB / 128), 256, 0, stream>>>(
            hbuf + (size_t)b * RB * TDR, TDR, w2b, qkvb, 0, 6144, TDR);
        postKV<<<TNH * 64, 256, 0, stream>>>(qkvb, ct, st, part);
        scanB128<<<(TNH * 128) / 256, 256, 0, stream>>>(part);
        scanCQ<<<TNH * 32, 64, 0, stream>>>(qkvb, part, ybuf + (size_t)b * RB * 2048, ct, st);
    }

    // all-rows tail: gemm3 (y -> t1), fused gemm4+final -> f32 out
    gemm_sk<0, 4><<<(ROWS / 128) * (TDR / 64), 256, 0, stream>>>(
        ybuf, 2048, wp1b, t1, TDR, TDQKV);
    gemm4f128<<<(ROWS / 128) * (TC / 64), 256, 0, stream>>>(t1, wp2b, x, out);
}